// Round 10
// baseline (25667.316 us; speedup 1.0000x reference)
//
#include <hip/hip_runtime.h>
#include <math.h>

#define EMBD 128
#define HIDD 128
#define NTAR 16
#define BSEQ 4096
#define G4   512
#define CH   8
#define MAGIC 0x13572468u

#define NPROD BSEQ                       // producer blocks (one per timestep)
#define NFC   ((BSEQ * NTAR) / 512)      // 128 FC blocks of 512 threads

typedef _Float16 v2h __attribute__((ext_vector_type(2)));

// Quad-lane butterfly add (validated R5-R9): 0xB1=[1,0,3,2], 0x4E=[2,3,0,1].
#define DPP_ADD(x, ctrl)                                                     \
    ((x) + __int_as_float(__builtin_amdgcn_update_dpp(                       \
               0, __float_as_int(x), (ctrl), 0xf, 0xf, true)))
// Quad-lane broadcast of lane g's value: ctrl = 0x00/0x55/0xAA/0xFF.
#define DPP_BCAST(x, ctrl)                                                   \
    (__int_as_float(__builtin_amdgcn_update_dpp(                             \
         0, __float_as_int(x), (ctrl), 0xf, 0xf, true)))

__device__ __forceinline__ float fast_tanh(float z) {
    return 1.f - 2.f * __builtin_amdgcn_rcpf(1.f + __expf(2.f * z));
}
__device__ __forceinline__ v2h pack_f16(float f0, float f1) {
    return __builtin_bit_cast(v2h, __builtin_amdgcn_cvt_pkrtz(f0, f1));
}

// ---------------------------------------------------------------------------
// ONE fused kernel. Block 0: sequential LSTM (inner loop identical to R9).
// Blocks 1..4096: input projection for timestep blockIdx-1, then release
// flag[t]=MAGIC (agent scope). Blocks 4097..: FC, sleep-spin on done-flag.
// d_ws poison is 0xAAAAAAAA != MAGIC, so flags need no initialization.
// Producers depend on nothing -> no circular wait; ~3 blocks/CU x 256 CUs
// leaves >600 slots for producers while 129 blocks spin.
// ---------------------------------------------------------------------------
__global__ __launch_bounds__(512, 2)
void fused_kernel(const int* __restrict__ x,
                  const float* __restrict__ emb,
                  const float* __restrict__ w_ih,
                  const float* __restrict__ b_ih,
                  const float* __restrict__ b_hh,
                  const float* __restrict__ w_hh,
                  const float* __restrict__ w_fc,
                  const float* __restrict__ b_fc,
                  float* __restrict__ zxT,
                  _Float16* __restrict__ hs16,
                  unsigned* __restrict__ flags,   // [BSEQ]
                  unsigned* __restrict__ done,    // [1]
                  float* __restrict__ out) {
    const int blk = blockIdx.x;
    const int tid = threadIdx.x;

    // ======================= producers: input projection ====================
    if (blk >= 1 && blk <= NPROD) {
        const int t = blk - 1;
        const int j = tid;                // 0..511
        const int u = j >> 2;
        const int g = j & 3;
        const int row = g * HIDD + u;
        const int idx = x[t];
        const float4* __restrict__ er =
            (const float4*)(emb + (long long)idx * EMBD);
        const float4* __restrict__ wr = (const float4*)(w_ih + row * EMBD);
        float acc = 0.f;
#pragma unroll
        for (int k = 0; k < EMBD / 4; ++k) {
            float4 e = er[k];
            float4 w = wr[k];
            acc += e.x * w.x + e.y * w.y + e.z * w.z + e.w * w.w;
        }
        zxT[t * G4 + j] = acc + b_ih[row] + b_hh[row];
        __threadfence();                  // writes visible at agent scope
        __syncthreads();                  // all 512 writes done
        if (tid == 0)
            __hip_atomic_store(&flags[t], MAGIC, __ATOMIC_RELEASE,
                               __HIP_MEMORY_SCOPE_AGENT);
        return;
    }

    // ============================ FC blocks ================================
    if (blk > NPROD) {
        if (tid == 0) {
            while (__hip_atomic_load(done, __ATOMIC_ACQUIRE,
                                     __HIP_MEMORY_SCOPE_AGENT) != MAGIC)
                __builtin_amdgcn_s_sleep(8);
        }
        __syncthreads();
        const int e = (blk - NPROD - 1) * 512 + tid;   // 0..65535
        const int n = e & (NTAR - 1);
        const int t = e >> 4;
        const v2h*    __restrict__ h2 = (const v2h*)(hs16 + t * HIDD);
        const float2* __restrict__ w2 = (const float2*)(w_fc + n * HIDD);
        float acc = b_fc[n];
#pragma unroll
        for (int k = 0; k < HIDD / 2; ++k) {
            const v2h   h = h2[k];
            const float2 w = w2[k];
            acc += (float)h.x * w.x + (float)h.y * w.y;
        }
        out[e] = acc;
        return;
    }

    // ======================= block 0: sequential LSTM =======================
    __shared__ __align__(16) _Float16 h_db[2][HIDD];

    const int l   = tid & 63;
    const int wv  = tid >> 6;
    const int kq  = l & 3;               // k-quarter AND this lane's gate
    const int us  = l >> 2;              // unit-sub 0..15
    const int u   = wv * 16 + us;        // hidden unit 0..127
    const bool writer = (kq == 0);

    // Lane-constant activation coefficients (hoisted predication).
    const float mA = (kq == 2) ? 2.f : -1.f;
    const float cA = (kq == 2) ? -2.f : 1.f;
    const float cB = (kq == 2) ? 1.f : 0.f;

    // Weights as half2, chunk-rotated (R6/R8 bank-disjoint pattern).
    v2h w2h[4][16];
#pragma unroll
    for (int g = 0; g < 4; ++g) {
        const float* __restrict__ wr = w_hh + (g * HIDD + u) * HIDD + 32 * kq;
#pragma unroll
        for (int j = 0; j < 4; ++j) {
            const int c0 = 8 * ((j + kq) & 3);
#pragma unroll
            for (int p = 0; p < 4; ++p)
                w2h[g][4 * j + p] = pack_f16(wr[c0 + 2 * p], wr[c0 + 2 * p + 1]);
        }
    }
#pragma unroll
    for (int g = 0; g < 4; ++g)
#pragma unroll
        for (int k = 0; k < 16; ++k)
            asm volatile("" : "+v"(w2h[g][k]));   // pin: no rematerialization

    if (tid < HIDD) {
        h_db[0][tid] = (_Float16)0.f;
        h_db[1][tid] = (_Float16)0.f;
    }
    float c = 0.f;
    float hreg[CH];
    float zcur[CH], zfut[CH];
    const int zoff = wv * 64 + l;        // per-lane zx scalar stream

    // Wait for chunk 0, then preload it.
    {
        bool ready = false;
        while (!ready) {
            ready = true;
#pragma unroll
            for (int s = 0; s < CH; ++s)
                ready &= (__hip_atomic_load(&flags[s], __ATOMIC_ACQUIRE,
                                            __HIP_MEMORY_SCOPE_AGENT) == MAGIC);
            if (!ready) __builtin_amdgcn_s_sleep(2);
        }
    }
#pragma unroll
    for (int s = 0; s < CH; ++s) {
        zcur[s] = zxT[s * G4 + zoff];
        hreg[s] = 0.f;
    }
    __syncthreads();

    for (int tc = 0; tc < BSEQ; tc += CH) {
        // Batch-store previous chunk's h as f16 (one lane per unit).
        if (writer && tc > 0) {
#pragma unroll
            for (int s = 0; s < CH; ++s)
                hs16[(tc - CH + s) * HIDD + u] = (_Float16)hreg[s];
        }
        // Spin-acquire NEXT chunk's flags, then prefetch its zx scalars.
        {
            const int tn = (tc + CH < BSEQ) ? (tc + CH) : (BSEQ - CH);
            bool ready = false;
            while (!ready) {
                ready = true;
#pragma unroll
                for (int s = 0; s < CH; ++s)
                    ready &= (__hip_atomic_load(&flags[tn + s], __ATOMIC_ACQUIRE,
                                                __HIP_MEMORY_SCOPE_AGENT) == MAGIC);
                if (!ready) __builtin_amdgcn_s_sleep(2);
            }
#pragma unroll
            for (int s = 0; s < CH; ++s)
                zfut[s] = zxT[(tn + s) * G4 + zoff];
        }

#pragma unroll
        for (int s = 0; s < CH; ++s) {
            const uint4* __restrict__ rb =
                (const uint4*)(&h_db[s & 1][32 * kq]);
            const int wb = (s & 1) ^ 1;

            float z0a = 0.f, z1a = 0.f, z2a = 0.f, z3a = 0.f;
            float z0b = 0.f, z1b = 0.f, z2b = 0.f, z3b = 0.f;
#pragma unroll
            for (int j = 0; j < 4; ++j) {
                const int cj = (j + kq) & 3;
                const uint4 hb = rb[cj];                 // ds_read_b128
                v2h hp[4];
                hp[0] = __builtin_bit_cast(v2h, hb.x);
                hp[1] = __builtin_bit_cast(v2h, hb.y);
                hp[2] = __builtin_bit_cast(v2h, hb.z);
                hp[3] = __builtin_bit_cast(v2h, hb.w);
                if (j < 2) {
#pragma unroll
                    for (int p = 0; p < 4; ++p) {
                        z0a = __builtin_amdgcn_fdot2(hp[p], w2h[0][4 * j + p], z0a, false);
                        z1a = __builtin_amdgcn_fdot2(hp[p], w2h[1][4 * j + p], z1a, false);
                        z2a = __builtin_amdgcn_fdot2(hp[p], w2h[2][4 * j + p], z2a, false);
                        z3a = __builtin_amdgcn_fdot2(hp[p], w2h[3][4 * j + p], z3a, false);
                    }
                } else {
#pragma unroll
                    for (int p = 0; p < 4; ++p) {
                        z0b = __builtin_amdgcn_fdot2(hp[p], w2h[0][4 * j + p], z0b, false);
                        z1b = __builtin_amdgcn_fdot2(hp[p], w2h[1][4 * j + p], z1b, false);
                        z2b = __builtin_amdgcn_fdot2(hp[p], w2h[2][4 * j + p], z2b, false);
                        z3b = __builtin_amdgcn_fdot2(hp[p], w2h[3][4 * j + p], z3b, false);
                    }
                }
            }
            float z0 = z0a + z0b, z1 = z1a + z1b;
            float z2 = z2a + z2b, z3 = z3a + z3b;

            z0 = DPP_ADD(z0, 0xB1); z0 = DPP_ADD(z0, 0x4E);
            z1 = DPP_ADD(z1, 0xB1); z1 = DPP_ADD(z1, 0x4E);
            z2 = DPP_ADD(z2, 0xB1); z2 = DPP_ADD(z2, 0x4E);
            z3 = DPP_ADD(z3, 0xB1); z3 = DPP_ADD(z3, 0x4E);

            // Lane kq finishes only gate kq (1 exp + 1 rcp), then quad bcast.
            float zs = z0;
            zs = (kq == 1) ? z1 : zs;
            zs = (kq == 2) ? z2 : zs;
            zs = (kq == 3) ? z3 : zs;
            const float zfull = zs + zcur[s];
            const float r   = __builtin_amdgcn_rcpf(1.f + __expf(mA * zfull));
            const float act = fmaf(cA, r, cB);

            const float gi = DPP_BCAST(act, 0x00);
            const float gf = DPP_BCAST(act, 0x55);
            const float gg = DPP_BCAST(act, 0xAA);
            const float go = DPP_BCAST(act, 0xFF);

            c = gf * c + gi * gg;
            const float h = go * fast_tanh(c);
            hreg[s] = h;
            if (writer) h_db[wb][u] = (_Float16)h;
            __syncthreads();
        }
#pragma unroll
        for (int s = 0; s < CH; ++s) zcur[s] = zfut[s];
    }
    if (writer) {
#pragma unroll
        for (int s = 0; s < CH; ++s)
            hs16[(BSEQ - CH + s) * HIDD + u] = (_Float16)hreg[s];
    }
    // Release the FC blocks.
    __threadfence();
    __syncthreads();
    if (tid == 0)
        __hip_atomic_store(done, MAGIC, __ATOMIC_RELEASE,
                           __HIP_MEMORY_SCOPE_AGENT);
}

// ---------------------------------------------------------------------------
extern "C" void kernel_launch(void* const* d_in, const int* in_sizes, int n_in,
                              void* d_out, int out_size, void* d_ws, size_t ws_size,
                              hipStream_t stream) {
    const int*   x    = (const int*)d_in[0];
    const float* emb  = (const float*)d_in[1];
    const float* w_ih = (const float*)d_in[2];
    const float* w_hh = (const float*)d_in[3];
    const float* b_ih = (const float*)d_in[4];
    const float* b_hh = (const float*)d_in[5];
    const float* w_fc = (const float*)d_in[6];
    const float* b_fc = (const float*)d_in[7];
    float* out = (float*)d_out;

    // Workspace (within the 10 MB proven safe in R1-R9):
    //   zxT   f32 [BSEQ*512]  : 8 MB      @ 0
    //   hs16  f16 [BSEQ*128]  : 1 MB      @ 8 MB
    //   flags u32 [BSEQ]      : 16 KB     @ 9 MB
    //   done  u32 [1]                     @ 9 MB + 16 KB
    char* ws = (char*)d_ws;
    float*     zxT   = (float*)ws;
    _Float16*  hs16  = (_Float16*)(ws + (size_t)8 * 1024 * 1024);
    unsigned*  flags = (unsigned*)(ws + (size_t)9 * 1024 * 1024);
    unsigned*  done  = flags + BSEQ;

    fused_kernel<<<1 + NPROD + NFC, 512, 0, stream>>>(
        x, emb, w_ih, b_ih, b_hh, w_hh, w_fc, b_fc,
        zxT, hs16, flags, done, out);
}

// Round 11
// 2488.971 us; speedup vs baseline: 10.3124x; 10.3124x over previous
//
#include <hip/hip_runtime.h>
#include <math.h>

#define EMBD 128
#define HIDD 128
#define NTAR 16
#define BSEQ 4096
#define G4   512
#define CH   8            // zx load / hs store batch (amortizes barrier vmcnt drain)

typedef _Float16 v2h __attribute__((ext_vector_type(2)));

// Quad-lane butterfly add (validated R5-R9): 0xB1=[1,0,3,2], 0x4E=[2,3,0,1].
#define DPP_ADD(x, ctrl)                                                     \
    ((x) + __int_as_float(__builtin_amdgcn_update_dpp(                       \
               0, __float_as_int(x), (ctrl), 0xf, 0xf, true)))
// Quad-lane broadcast of lane g's value: ctrl = 0x00/0x55/0xAA/0xFF.
#define DPP_BCAST(x, ctrl)                                                   \
    (__int_as_float(__builtin_amdgcn_update_dpp(                             \
         0, __float_as_int(x), (ctrl), 0xf, 0xf, true)))

__device__ __forceinline__ float fast_tanh(float z) {
    return 1.f - 2.f * __builtin_amdgcn_rcpf(1.f + __expf(2.f * z));
}
__device__ __forceinline__ v2h pack_f16(float f0, float f1) {
    return __builtin_bit_cast(v2h, __builtin_amdgcn_cvt_pkrtz(f0, f1));
}

// ---------------------------------------------------------------------------
// Kernel 1: input projection, transposed layout (fp32 — zx precision anchor).
// zxT[(t*128 + u)*4 + g] = dot(emb[x[t]], w_ih[g*128+u]) + b_ih + b_hh
// ---------------------------------------------------------------------------
__global__ void input_proj_kernel(const int* __restrict__ x,
                                  const float* __restrict__ emb,
                                  const float* __restrict__ w_ih,
                                  const float* __restrict__ b_ih,
                                  const float* __restrict__ b_hh,
                                  float* __restrict__ zxT) {
    const int t = blockIdx.x;
    const int j = threadIdx.x;            // 0..511
    const int u = j >> 2;
    const int g = j & 3;
    const int row = g * HIDD + u;
    const int idx = x[t];
    const float4* __restrict__ er = (const float4*)(emb + (long long)idx * EMBD);
    const float4* __restrict__ wr = (const float4*)(w_ih + row * EMBD);
    float acc = 0.f;
#pragma unroll
    for (int k = 0; k < EMBD / 4; ++k) {
        float4 e = er[k];
        float4 w = wr[k];
        acc += e.x * w.x + e.y * w.y + e.z * w.z + e.w * w.w;
    }
    zxT[(t * HIDD + u) * 4 + g] = acc + b_ih[row] + b_hh[row];
}

// ---------------------------------------------------------------------------
// Kernel 2: sequential LSTM. 256 threads (4 waves, 1/SIMD), one barrier/step.
//
// R10 post-mortem: intra-kernel spin-flag fusion = 10x regression (agent-
// scope acquire round-trips + device-wide polling). Reverted. R9 model:
// step = 1237 cyc with ~480 issue/SIMD; the rest is the CU-shared LDS pipe
// (32 ds_read_b128/step), 8-wave barrier skew, and unhidden chain latency.
// R11: HALVE the wave count — each thread owns 2 units (u0, u1 = u0+16),
// reading its 64 B h-quarter ONCE for both. LDS instrs/step 32 -> 16,
// barrier participants 8 -> 4 waves, per-SIMD fdot2 issue unchanged
// (128 x 4 cyc), math bit-identical to R9.
//
// Lane layout: l = tid&63, wv = tid>>6 (0..3); kq = l&3 (k-quarter AND
// this lane's gate), us = l>>2; u0 = wv*32 + us, u1 = u0 + 16.
// Weights: 2 units x 4 gates x 16 v2h = 128 VGPRs, pinned (1 wave/SIMD
// allows up to 512 VGPRs).
// ---------------------------------------------------------------------------
__global__ __launch_bounds__(256, 1)
void lstm_seq_kernel(const float* __restrict__ zxT,
                     const float* __restrict__ w_hh,
                     float* __restrict__ hs) {
    __shared__ __align__(16) _Float16 h_db[2][HIDD];

    const int tid = threadIdx.x;
    const int l   = tid & 63;
    const int wv  = tid >> 6;            // 0..3
    const int kq  = l & 3;               // k-quarter AND this lane's gate
    const int us  = l >> 2;              // 0..15
    const int u0  = wv * 32 + us;        // first owned unit
    const int u1  = u0 + 16;             // second owned unit
    const bool writer = (kq == 0);

    // Lane-constant activation coefficients (hoisted predication):
    // sigmoid(z) = rcp(1+exp(-z));  tanh(z) = 1 - 2*rcp(1+exp(2z)).
    const float mA = (kq == 2) ? 2.f : -1.f;
    const float cA = (kq == 2) ? -2.f : 1.f;
    const float cB = (kq == 2) ? 1.f : 0.f;

    // Weights as half2, chunk-rotated (R6/R8 bank-disjoint pattern):
    // w2h[unit][g][4*j + p] covers cols 32kq + 8*((j+kq)&3) + 2p .. +1.
    v2h w2h[2][4][16];
#pragma unroll
    for (int un = 0; un < 2; ++un) {
        const int u = un ? u1 : u0;
#pragma unroll
        for (int g = 0; g < 4; ++g) {
            const float* __restrict__ wr =
                w_hh + (g * HIDD + u) * HIDD + 32 * kq;
#pragma unroll
            for (int j = 0; j < 4; ++j) {
                const int c0 = 8 * ((j + kq) & 3);
#pragma unroll
                for (int p = 0; p < 4; ++p)
                    w2h[un][g][4 * j + p] =
                        pack_f16(wr[c0 + 2 * p], wr[c0 + 2 * p + 1]);
            }
        }
    }
#pragma unroll
    for (int un = 0; un < 2; ++un)
#pragma unroll
        for (int g = 0; g < 4; ++g)
#pragma unroll
            for (int k = 0; k < 16; ++k)
                asm volatile("" : "+v"(w2h[un][g][k]));  // pin in registers

    if (tid < HIDD) {
        h_db[0][tid] = (_Float16)0.f;
        h_db[1][tid] = (_Float16)0.f;
    }
    float c0r = 0.f, c1r = 0.f;
    float hreg0[CH], hreg1[CH];
    float zcur0[CH], zcur1[CH], zfut0[CH], zfut1[CH];
    // Per-lane zx scalar streams (coalesced): addr = t*512 + wv*128 + l (+64).
    const int zoff0 = wv * 128 + l;
    const int zoff1 = zoff0 + 64;
#pragma unroll
    for (int s = 0; s < CH; ++s) {
        zcur0[s] = zxT[s * G4 + zoff0];
        zcur1[s] = zxT[s * G4 + zoff1];
        hreg0[s] = 0.f;
        hreg1[s] = 0.f;
    }
    __syncthreads();

    for (int tc = 0; tc < BSEQ; tc += CH) {
        // Batch-store previous chunk's h (writer lanes, coalesced).
        if (writer && tc > 0) {
#pragma unroll
            for (int s = 0; s < CH; ++s) {
                hs[(tc - CH + s) * HIDD + u0] = hreg0[s];
                hs[(tc - CH + s) * HIDD + u1] = hreg1[s];
            }
        }
        // Prefetch NEXT chunk's zx scalars (a full chunk of latency).
        {
            const int tn = (tc + CH < BSEQ) ? (tc + CH) : (BSEQ - CH);
#pragma unroll
            for (int s = 0; s < CH; ++s) {
                zfut0[s] = zxT[(tn + s) * G4 + zoff0];
                zfut1[s] = zxT[(tn + s) * G4 + zoff1];
            }
        }

#pragma unroll
        for (int s = 0; s < CH; ++s) {
            // tc multiple of CH (even) -> buffer parity compile-time s&1.
            const uint4* __restrict__ rb =
                (const uint4*)(&h_db[s & 1][32 * kq]);   // 4 uint4 chunks
            const int wb = (s & 1) ^ 1;

            // Split accumulators per unit/gate: halve fdot2 chain depth.
            float za[2][4] = {{0.f,0.f,0.f,0.f},{0.f,0.f,0.f,0.f}};
            float zbb[2][4] = {{0.f,0.f,0.f,0.f},{0.f,0.f,0.f,0.f}};
#pragma unroll
            for (int j = 0; j < 4; ++j) {
                const int cj = (j + kq) & 3;             // rotated chunk
                const uint4 hb = rb[cj];                 // ds_read_b128
                v2h hp[4];
                hp[0] = __builtin_bit_cast(v2h, hb.x);
                hp[1] = __builtin_bit_cast(v2h, hb.y);
                hp[2] = __builtin_bit_cast(v2h, hb.z);
                hp[3] = __builtin_bit_cast(v2h, hb.w);
                if (j < 2) {
#pragma unroll
                    for (int p = 0; p < 4; ++p)
#pragma unroll
                        for (int un = 0; un < 2; ++un)
#pragma unroll
                            for (int g = 0; g < 4; ++g)
                                za[un][g] = __builtin_amdgcn_fdot2(
                                    hp[p], w2h[un][g][4 * j + p], za[un][g], false);
                } else {
#pragma unroll
                    for (int p = 0; p < 4; ++p)
#pragma unroll
                        for (int un = 0; un < 2; ++un)
#pragma unroll
                            for (int g = 0; g < 4; ++g)
                                zbb[un][g] = __builtin_amdgcn_fdot2(
                                    hp[p], w2h[un][g][4 * j + p], zbb[un][g], false);
                }
            }
            float z0[4], z1[4];
#pragma unroll
            for (int g = 0; g < 4; ++g) {
                z0[g] = za[0][g] + zbb[0][g];
                z1[g] = za[1][g] + zbb[1][g];
            }

            // Quad butterfly per unit/gate.
#pragma unroll
            for (int g = 0; g < 4; ++g) {
                z0[g] = DPP_ADD(z0[g], 0xB1); z0[g] = DPP_ADD(z0[g], 0x4E);
                z1[g] = DPP_ADD(z1[g], 0xB1); z1[g] = DPP_ADD(z1[g], 0x4E);
            }

            // Lane kq finishes gate kq for both units (2 exp + 2 rcp).
            float zs0 = z0[0], zs1 = z1[0];
            zs0 = (kq == 1) ? z0[1] : zs0;  zs1 = (kq == 1) ? z1[1] : zs1;
            zs0 = (kq == 2) ? z0[2] : zs0;  zs1 = (kq == 2) ? z1[2] : zs1;
            zs0 = (kq == 3) ? z0[3] : zs0;  zs1 = (kq == 3) ? z1[3] : zs1;
            const float zf0 = zs0 + zcur0[s];
            const float zf1 = zs1 + zcur1[s];
            const float r0   = __builtin_amdgcn_rcpf(1.f + __expf(mA * zf0));
            const float r1   = __builtin_amdgcn_rcpf(1.f + __expf(mA * zf1));
            const float act0 = fmaf(cA, r0, cB);
            const float act1 = fmaf(cA, r1, cB);

            // Broadcast the 4 gate acts across the quad, per unit.
            const float gi0 = DPP_BCAST(act0, 0x00);
            const float gf0 = DPP_BCAST(act0, 0x55);
            const float gg0 = DPP_BCAST(act0, 0xAA);
            const float go0 = DPP_BCAST(act0, 0xFF);
            const float gi1 = DPP_BCAST(act1, 0x00);
            const float gf1 = DPP_BCAST(act1, 0x55);
            const float gg1 = DPP_BCAST(act1, 0xAA);
            const float go1 = DPP_BCAST(act1, 0xFF);

            c0r = gf0 * c0r + gi0 * gg0;
            c1r = gf1 * c1r + gi1 * gg1;
            const float h0 = go0 * fast_tanh(c0r);
            const float h1 = go1 * fast_tanh(c1r);
            hreg0[s] = h0;
            hreg1[s] = h1;
            if (writer) {
                h_db[wb][u0] = (_Float16)h0;
                h_db[wb][u1] = (_Float16)h1;
            }
            __syncthreads();                 // the one barrier per step
        }
#pragma unroll
        for (int s = 0; s < CH; ++s) {
            zcur0[s] = zfut0[s];
            zcur1[s] = zfut1[s];
        }
    }
    if (writer) {
#pragma unroll
        for (int s = 0; s < CH; ++s) {
            hs[(BSEQ - CH + s) * HIDD + u0] = hreg0[s];
            hs[(BSEQ - CH + s) * HIDD + u1] = hreg1[s];
        }
    }
}

// ---------------------------------------------------------------------------
// Kernel 3: final FC. out[t][n] = dot(hs[t], w_fc[n]) + b_fc[n].
// ---------------------------------------------------------------------------
__global__ void fc_kernel(const float* __restrict__ hs,
                          const float* __restrict__ w_fc,
                          const float* __restrict__ b_fc,
                          float* __restrict__ out) {
    const int gid = blockIdx.x * blockDim.x + threadIdx.x;
    if (gid >= BSEQ * NTAR) return;
    const int n = gid & (NTAR - 1);
    const int t = gid >> 4;
    const float4* __restrict__ hr = (const float4*)(hs + t * HIDD);
    const float4* __restrict__ wr = (const float4*)(w_fc + n * HIDD);
    float acc = 0.f;
#pragma unroll
    for (int k = 0; k < HIDD / 4; ++k) {
        float4 h = hr[k];
        float4 wv = wr[k];
        acc += h.x * wv.x + h.y * wv.y + h.z * wv.z + h.w * wv.w;
    }
    out[gid] = acc + b_fc[n];
}

// ---------------------------------------------------------------------------
extern "C" void kernel_launch(void* const* d_in, const int* in_sizes, int n_in,
                              void* d_out, int out_size, void* d_ws, size_t ws_size,
                              hipStream_t stream) {
    const int*   x    = (const int*)d_in[0];
    const float* emb  = (const float*)d_in[1];
    const float* w_ih = (const float*)d_in[2];
    const float* w_hh = (const float*)d_in[3];
    const float* b_ih = (const float*)d_in[4];
    const float* b_hh = (const float*)d_in[5];
    const float* w_fc = (const float*)d_in[6];
    const float* b_fc = (const float*)d_in[7];
    float* out = (float*)d_out;

    // Workspace: zxT (4096*512 f32 = 8 MB) | hs (4096*128 f32 = 2 MB)
    float* zxT = (float*)d_ws;
    float* hs  = zxT + (size_t)BSEQ * G4;

    input_proj_kernel<<<BSEQ, G4, 0, stream>>>(x, emb, w_ih, b_ih, b_hh, zxT);
    lstm_seq_kernel<<<1, 256, 0, stream>>>(zxT, w_hh, hs);
    fc_kernel<<<(BSEQ * NTAR + 255) / 256, 256, 0, stream>>>(hs, w_fc, b_fc, out);
}

// Round 12
// 2096.126 us; speedup vs baseline: 12.2451x; 1.1874x over previous
//
#include <hip/hip_runtime.h>
#include <math.h>

#define EMBD 128
#define HIDD 128
#define NTAR 16
#define BSEQ 4096
#define G4   512
#define CH   8            // zx load / hs store batch (amortizes barrier vmcnt drain)

typedef _Float16 v8h __attribute__((ext_vector_type(8)));
typedef float    v4f __attribute__((ext_vector_type(4)));

__device__ __forceinline__ float fast_sigmoid(float z) {
    return __builtin_amdgcn_rcpf(1.f + __expf(-z));
}
__device__ __forceinline__ float fast_tanh(float z) {
    return 1.f - 2.f * __builtin_amdgcn_rcpf(1.f + __expf(2.f * z));
}

// ---------------------------------------------------------------------------
// Kernel 1: input projection, transposed layout (fp32 — zx precision anchor).
// zxT[(t*128 + u)*4 + g] = dot(emb[x[t]], w_ih[g*128+u]) + b_ih + b_hh
// ---------------------------------------------------------------------------
__global__ void input_proj_kernel(const int* __restrict__ x,
                                  const float* __restrict__ emb,
                                  const float* __restrict__ w_ih,
                                  const float* __restrict__ b_ih,
                                  const float* __restrict__ b_hh,
                                  float* __restrict__ zxT) {
    const int t = blockIdx.x;
    const int j = threadIdx.x;            // 0..511
    const int u = j >> 2;
    const int g = j & 3;
    const int row = g * HIDD + u;
    const int idx = x[t];
    const float4* __restrict__ er = (const float4*)(emb + (long long)idx * EMBD);
    const float4* __restrict__ wr = (const float4*)(w_ih + row * EMBD);
    float acc = 0.f;
#pragma unroll
    for (int k = 0; k < EMBD / 4; ++k) {
        float4 e = er[k];
        float4 w = wr[k];
        acc += e.x * w.x + e.y * w.y + e.z * w.z + e.w * w.w;
    }
    zxT[(t * HIDD + u) * 4 + g] = acc + b_ih[row] + b_hh[row];
}

// ---------------------------------------------------------------------------
// Kernel 2: sequential LSTM via MFMA. 512 threads (8 waves, 2/SIMD).
//
// R9/R11 post-mortem: any VALU-MAC variant is pinned at 512 cyc/CU/step of
// MAC issue (fdot2 / pk_fma = 32 MACs/cyc/SIMD). MFMA does ~1700 MACs/cyc
// /CU: per step compute z^T = h^T (1x128) @ W_hh^T (128x512) as 16 MFMAs
// per wave (4 gate N-tiles x 4 K-chunks of v_mfma_f32_16x16x32_f16).
//
// Wave w owns units [16w, 16w+16). B-frag (g,q), lane (n=l&15, qd=l>>4):
//   B[k=q*32+qd*8+j][n] = W_hh[g*128+U0+n][q*32+qd*8+j]  (8 f16, pinned).
// A-frag q: row 0 = h only. Quad-leader lanes (l&15==0) ds_read_b128
// h[q*32+qd*8 .. +7]; ALL other lanes read a zeroed 16B LDS pad -> A rows
// 1..15 are zero with no cndmask cost.
// D layout (m89-verified, dtype-independent): col=lane&15, row=qd*4+reg.
// Row 0 lives in lanes 0..15 reg 0 -> after the 4 gate tiles, lane u<16
// holds ALL FOUR gate z's of unit U0+u: gates + c/h update stay in-lane
// (no DPP redistribution), h written by 16 lanes/wave (2 f16/bank = free).
// One barrier/step; h_db double-buffered; CH=8 zx/hs batching as R9.
// ---------------------------------------------------------------------------
__global__ __launch_bounds__(512, 2)
void lstm_seq_kernel(const float* __restrict__ zxT,
                     const float* __restrict__ w_hh,
                     float* __restrict__ hs) {
    __shared__ __align__(16) _Float16 h_db[2][HIDD];
    __shared__ __align__(16) _Float16 zpad[8];    // stays zero forever

    const int tid = threadIdx.x;
    const int l   = tid & 63;
    const int wv  = tid >> 6;            // 0..7
    const int n   = l & 15;              // unit-sub / MFMA col
    const int qd  = l >> 4;              // quad id 0..3
    const int U0  = wv * 16;             // this wave's unit block
    const int u   = U0 + n;
    const bool lane16 = (l < 16);        // holds valid z/h (row 0 lanes)

    // B-fragments: b[g][q], 8 f16 each = 64 VGPRs total. Pinned.
    v8h b[4][4];
#pragma unroll
    for (int g = 0; g < 4; ++g) {
#pragma unroll
        for (int q = 0; q < 4; ++q) {
            const float* __restrict__ wr =
                w_hh + (g * HIDD + u) * HIDD + q * 32 + qd * 8;
            v8h f;
#pragma unroll
            for (int j = 0; j < 8; ++j) f[j] = (_Float16)wr[j];
            b[g][q] = f;
        }
    }
#pragma unroll
    for (int g = 0; g < 4; ++g)
#pragma unroll
        for (int q = 0; q < 4; ++q)
            asm volatile("" : "+v"(b[g][q]));     // no rematerialization

    if (tid < HIDD) { h_db[0][tid] = (_Float16)0.f; h_db[1][tid] = (_Float16)0.f; }
    if (tid < 8)    zpad[tid] = (_Float16)0.f;

    // A-frag source addresses: leader lanes walk h, others pinned at zpad.
    const bool leader = (n == 0);
    const _Float16* abase0 = leader ? &h_db[0][qd * 8] : &zpad[0];
    const _Float16* abase1 = leader ? &h_db[1][qd * 8] : &zpad[0];
    const int astep = leader ? 32 : 0;            // halves per K-chunk

    float c = 0.f;
    float hreg[CH];
    float4 zcur[CH], zfut[CH];
    const float4* __restrict__ zx4 = (const float4*)zxT;
#pragma unroll
    for (int s = 0; s < CH; ++s) {
        zcur[s] = zx4[s * HIDD + u];     // lanes 16-63 duplicate lane n
        hreg[s] = 0.f;
    }
    __syncthreads();

    for (int tc = 0; tc < BSEQ; tc += CH) {
        // Batch-store previous chunk's h (16 lanes/wave, coalesced 64B).
        if (lane16 && tc > 0) {
#pragma unroll
            for (int s = 0; s < CH; ++s)
                hs[(tc - CH + s) * HIDD + u] = hreg[s];
        }
        // Prefetch NEXT chunk's zx rows (full chunk of latency hiding).
        {
            const int tn = (tc + CH < BSEQ) ? (tc + CH) : (BSEQ - CH);
#pragma unroll
            for (int s = 0; s < CH; ++s)
                zfut[s] = zx4[(tn + s) * HIDD + u];
        }

#pragma unroll
        for (int s = 0; s < CH; ++s) {
            const _Float16* ab = (s & 1) ? abase1 : abase0;
            const int wb = (s & 1) ^ 1;

            // A-frags: leaders read h slices, others read the zero pad.
            v8h a0 = *(const v8h*)(ab + 0 * astep);
            v8h a1 = *(const v8h*)(ab + 1 * astep);
            v8h a2 = *(const v8h*)(ab + 2 * astep);
            v8h a3 = *(const v8h*)(ab + 3 * astep);

            // 16 MFMAs: 4 gates x 4 K-chunks (4 independent acc chains).
            v4f d0 = {0.f, 0.f, 0.f, 0.f}, d1 = d0, d2 = d0, d3 = d0;
            d0 = __builtin_amdgcn_mfma_f32_16x16x32_f16(a0, b[0][0], d0, 0, 0, 0);
            d1 = __builtin_amdgcn_mfma_f32_16x16x32_f16(a0, b[1][0], d1, 0, 0, 0);
            d2 = __builtin_amdgcn_mfma_f32_16x16x32_f16(a0, b[2][0], d2, 0, 0, 0);
            d3 = __builtin_amdgcn_mfma_f32_16x16x32_f16(a0, b[3][0], d3, 0, 0, 0);
            d0 = __builtin_amdgcn_mfma_f32_16x16x32_f16(a1, b[0][1], d0, 0, 0, 0);
            d1 = __builtin_amdgcn_mfma_f32_16x16x32_f16(a1, b[1][1], d1, 0, 0, 0);
            d2 = __builtin_amdgcn_mfma_f32_16x16x32_f16(a1, b[2][1], d2, 0, 0, 0);
            d3 = __builtin_amdgcn_mfma_f32_16x16x32_f16(a1, b[3][1], d3, 0, 0, 0);
            d0 = __builtin_amdgcn_mfma_f32_16x16x32_f16(a2, b[0][2], d0, 0, 0, 0);
            d1 = __builtin_amdgcn_mfma_f32_16x16x32_f16(a2, b[1][2], d1, 0, 0, 0);
            d2 = __builtin_amdgcn_mfma_f32_16x16x32_f16(a2, b[2][2], d2, 0, 0, 0);
            d3 = __builtin_amdgcn_mfma_f32_16x16x32_f16(a2, b[3][2], d3, 0, 0, 0);
            d0 = __builtin_amdgcn_mfma_f32_16x16x32_f16(a3, b[0][3], d0, 0, 0, 0);
            d1 = __builtin_amdgcn_mfma_f32_16x16x32_f16(a3, b[1][3], d1, 0, 0, 0);
            d2 = __builtin_amdgcn_mfma_f32_16x16x32_f16(a3, b[2][3], d2, 0, 0, 0);
            d3 = __builtin_amdgcn_mfma_f32_16x16x32_f16(a3, b[3][3], d3, 0, 0, 0);

            // Lanes 0..15, reg 0 = row 0 = the matvec result per gate.
            const float4 zb = zcur[s];
            const float zi = d0[0] + zb.x;
            const float zf = d1[0] + zb.y;
            const float zg = d2[0] + zb.z;
            const float zo = d3[0] + zb.w;
            const float gi = fast_sigmoid(zi);
            const float gf = fast_sigmoid(zf);
            const float gg = fast_tanh(zg);
            const float go = fast_sigmoid(zo);
            c = gf * c + gi * gg;         // lanes 16-63: finite garbage, unused
            const float h = go * fast_tanh(c);
            hreg[s] = h;
            if (lane16) h_db[wb][u] = (_Float16)h;   // 2 f16/bank: free
            __syncthreads();              // the one barrier per step
        }
#pragma unroll
        for (int s = 0; s < CH; ++s) zcur[s] = zfut[s];
    }
    if (lane16) {
#pragma unroll
        for (int s = 0; s < CH; ++s)
            hs[(BSEQ - CH + s) * HIDD + u] = hreg[s];
    }
}

// ---------------------------------------------------------------------------
// Kernel 3: final FC. out[t][n] = dot(hs[t], w_fc[n]) + b_fc[n].
// ---------------------------------------------------------------------------
__global__ void fc_kernel(const float* __restrict__ hs,
                          const float* __restrict__ w_fc,
                          const float* __restrict__ b_fc,
                          float* __restrict__ out) {
    const int gid = blockIdx.x * blockDim.x + threadIdx.x;
    if (gid >= BSEQ * NTAR) return;
    const int n = gid & (NTAR - 1);
    const int t = gid >> 4;
    const float4* __restrict__ hr = (const float4*)(hs + t * HIDD);
    const float4* __restrict__ wr = (const float4*)(w_fc + n * HIDD);
    float acc = 0.f;
#pragma unroll
    for (int k = 0; k < HIDD / 4; ++k) {
        float4 h = hr[k];
        float4 wv = wr[k];
        acc += h.x * wv.x + h.y * wv.y + h.z * wv.z + h.w * wv.w;
    }
    out[gid] = acc + b_fc[n];
}

// ---------------------------------------------------------------------------
extern "C" void kernel_launch(void* const* d_in, const int* in_sizes, int n_in,
                              void* d_out, int out_size, void* d_ws, size_t ws_size,
                              hipStream_t stream) {
    const int*   x    = (const int*)d_in[0];
    const float* emb  = (const float*)d_in[1];
    const float* w_ih = (const float*)d_in[2];
    const float* w_hh = (const float*)d_in[3];
    const float* b_ih = (const float*)d_in[4];
    const float* b_hh = (const float*)d_in[5];
    const float* w_fc = (const float*)d_in[6];
    const float* b_fc = (const float*)d_in[7];
    float* out = (float*)d_out;

    // Workspace: zxT (4096*512 f32 = 8 MB) | hs (4096*128 f32 = 2 MB)
    float* zxT = (float*)d_ws;
    float* hs  = zxT + (size_t)BSEQ * G4;

    input_proj_kernel<<<BSEQ, G4, 0, stream>>>(x, emb, w_ih, b_ih, b_hh, zxT);
    lstm_seq_kernel<<<1, 512, 0, stream>>>(zxT, w_hh, hs);
    fc_kernel<<<(BSEQ * NTAR + 255) / 256, 256, 0, stream>>>(hs, w_fc, b_fc, out);
}